// Round 4
// baseline (257.013 us; speedup 1.0000x reference)
//
#include <hip/hip_runtime.h>
#include <hip/hip_bf16.h>
#include <cstdint>

// B=2, HW=64 -> 128 rows of S=256; M = 32768. D=512, HEADS=8, DK=64,
// 3*H*DK=1536, KSIZE=7. Inputs/outputs fp32; internal compute bf16 MFMA.

typedef __bf16 bf16x8 __attribute__((ext_vector_type(8)));
typedef float f32x4 __attribute__((ext_vector_type(4)));

__device__ __forceinline__ uint16_t f2bf(float f) {
    uint32_t u = __builtin_bit_cast(uint32_t, f);
    return (uint16_t)((u + 0x7fffu + ((u >> 16) & 1u)) >> 16);
}
__device__ __forceinline__ float bflo(uint32_t u) { return __builtin_bit_cast(float, u << 16); }
__device__ __forceinline__ float bfhi(uint32_t u) { return __builtin_bit_cast(float, u & 0xffff0000u); }

__device__ __forceinline__ void unpack8(uint4 v, float* f) {
    f[0] = bflo(v.x); f[1] = bfhi(v.x);
    f[2] = bflo(v.y); f[3] = bfhi(v.y);
    f[4] = bflo(v.z); f[5] = bfhi(v.z);
    f[6] = bflo(v.w); f[7] = bfhi(v.w);
}
__device__ __forceinline__ uint32_t pack2(float a, float b) {
    return (uint32_t)f2bf(a) | ((uint32_t)f2bf(b) << 16);
}

#define GLOAD_LDS16(gp, lp)                                                        \
    __builtin_amdgcn_global_load_lds((const __attribute__((address_space(1))) void*)(gp), \
                                     (__attribute__((address_space(3))) void*)(lp), 16, 0, 0)

// Inline-asm LDS read: invisible to the compiler's waitcnt/alias tracking.
// Volatile asm keeps mutual program order with the waitcnt/barrier asm, so the
// issue/wait counting below is exact. Caller owns lgkmcnt discipline.
__device__ __forceinline__ bf16x8 ds_read16(const uint16_t* p) {
    bf16x8 r;
    asm volatile("ds_read_b128 %0, %1"
                 : "=v"(r)
                 : "v"((const __attribute__((address_space(3))) void*)p));
    return r;
}

// ---------------------------------------------------------------------------
// fp32 -> bf16 bulk convert, 8 elems/thread
// ---------------------------------------------------------------------------
__global__ void cvt_f32_bf16(const float* __restrict__ in, uint16_t* __restrict__ out, int n8) {
    int i = blockIdx.x * 256 + threadIdx.x;
    if (i >= n8) return;
    const float4* p = (const float4*)in + (size_t)i * 2;
    float4 a = p[0], b = p[1];
    uint4 o;
    o.x = pack2(a.x, a.y);
    o.y = pack2(a.z, a.w);
    o.z = pack2(b.x, b.y);
    o.w = pack2(b.z, b.w);
    *((uint4*)out + i) = o;
}

// ---------------------------------------------------------------------------
// transpose + convert: out[c*R + r] = bf16(in[r*C + c])
// ---------------------------------------------------------------------------
__global__ void transpose_cvt(const float* __restrict__ in, uint16_t* __restrict__ out,
                              int R, int C) {
    int idx = blockIdx.x * 256 + threadIdx.x;
    if (idx >= R * C) return;
    int r = idx / C;
    int c = idx - r * C;
    out[(size_t)c * R + r] = f2bf(in[idx]);
}

// ---------------------------------------------------------------------------
// 256x256-tile bf16 GEMM, derived-wait pipeline (one barrier per K-tile).
// (unchanged from round 3 -- see comments there)
// ---------------------------------------------------------------------------
template <bool F32OUT>
__global__ __launch_bounds__(512, 2)
void gemm256(const uint16_t* __restrict__ A, const uint16_t* __restrict__ BT,
             void* __restrict__ Cout, int M, int N, int K) {
    __shared__ __align__(16) uint16_t lds[65536];  // [0,32768): A bufs, [32768,65536): B bufs

    const int tid  = threadIdx.x;
    const int lane = tid & 63;
    const int wv   = tid >> 6;
    const int r    = lane & 15;
    const int quad = lane >> 4;
    const int wr   = wv >> 2;   // 0..1  (M wave)
    const int wc   = wv & 3;    // 0..3  (N wave)
    const long bm0 = (long)blockIdx.x * 256;
    const long bn0 = (long)blockIdx.y * 256;
    const int NT   = K >> 6;

    // ---- staging constants: thread handles 16B chunks c0, c1 of each half ----
    const int c0 = tid, c1 = tid + 512;
    const int row0 = c0 >> 3, row1 = c1 >> 3;          // row within 128-row half
    const int sw0 = ((c0 & 7) ^ (row0 & 7)) * 8;       // pre-swizzled k-chunk (elems)
    const int sw1 = ((c1 & 7) ^ (row1 & 7)) * 8;
    const uint16_t* pA0 = A  + (bm0 + row0) * (long)K + sw0;
    const uint16_t* pA1 = A  + (bm0 + row1) * (long)K + sw1;
    const uint16_t* pB0 = BT + (bn0 + row0) * (long)K + sw0;
    const uint16_t* pB1 = BT + (bn0 + row1) * (long)K + sw1;
    const long hstep = 128 * (long)K;

#define STAGE_A(b_, h_, t_) do {                                                        \
        GLOAD_LDS16(pA0 + (h_) * hstep + (t_) * 64,                                     \
                    &lds[(b_) * 16384 + (h_) * 8192 + c0 * 8]);                         \
        GLOAD_LDS16(pA1 + (h_) * hstep + (t_) * 64,                                     \
                    &lds[(b_) * 16384 + (h_) * 8192 + c1 * 8]);                         \
    } while (0)
#define STAGE_B(b_, h_, t_) do {                                                        \
        GLOAD_LDS16(pB0 + (h_) * hstep + (t_) * 64,                                     \
                    &lds[32768 + (b_) * 16384 + (h_) * 8192 + c0 * 8]);                 \
        GLOAD_LDS16(pB1 + (h_) * hstep + (t_) * 64,                                     \
                    &lds[32768 + (b_) * 16384 + (h_) * 8192 + c1 * 8]);                 \
    } while (0)

    // ---- compute-side constants ----
    const int swk0 = ((0 + quad) ^ (r & 7)) * 8;   // kk=0 swizzled chunk (elems)
    const int swk1 = ((4 + quad) ^ (r & 7)) * 8;   // kk=1
    const int arow = (wr * 128 + r) * 64;          // elem offset of A row base
    const int brow = (wc * 64 + r) * 64;           // elem offset of B row base

#define DS_A(mf_, kk_) ds_read16(&lds[aoff + arow + (mf_) * 1024 + ((kk_) ? swk1 : swk0)])
#define DS_B(nf_, kk_) ds_read16(&lds[boff + brow + (nf_) * 1024 + ((kk_) ? swk1 : swk0)])

// counted wait + fence (rule #18: stop MFMA hoisting above the wait)
#define WAITK4 do { asm volatile("s_waitcnt lgkmcnt(4)" ::: "memory");                  \
                    __builtin_amdgcn_sched_barrier(0); } while (0)
#define WAITK0 do { asm volatile("s_waitcnt lgkmcnt(0)" ::: "memory");                  \
                    __builtin_amdgcn_sched_barrier(0); } while (0)

#define MFMA_CL(mbase_, ar_)                                                            \
    __builtin_amdgcn_s_setprio(1);                                                      \
    _Pragma("unroll")                                                                   \
    for (int kk = 0; kk < 2; ++kk)                                                      \
        _Pragma("unroll")                                                               \
        for (int mi = 0; mi < 2; ++mi)                                                  \
            _Pragma("unroll")                                                           \
            for (int nf = 0; nf < 4; ++nf)                                              \
                acc[(mbase_) + mi][nf] = __builtin_amdgcn_mfma_f32_16x16x32_bf16(       \
                    ar_[mi][kk], bfr[nf][kk], acc[(mbase_) + mi][nf], 0, 0, 0);         \
    __builtin_amdgcn_s_setprio(0);

    f32x4 acc[8][4];
#pragma unroll
    for (int mf = 0; mf < 8; ++mf)
#pragma unroll
        for (int nf = 0; nf < 4; ++nf) acc[mf][nf] = (f32x4){0.f, 0.f, 0.f, 0.f};

    // ---- prologue: stage tile0 into buf0, wait, barrier ----
    STAGE_A(0, 0, 0); STAGE_A(0, 1, 0);
    STAGE_B(0, 0, 0); STAGE_B(0, 1, 0);
    asm volatile("s_waitcnt vmcnt(0)" ::: "memory");
    __builtin_amdgcn_s_barrier();

    for (int t = 0; t < NT; ++t) {
        const int b    = t & 1;
        const int aoff = b * 16384;
        const int boff = 32768 + b * 16384;
        const bool pf  = (t + 1 < NT);

        bf16x8 bfr[4][2];
        bf16x8 a0[2][2], a1[2][2];

        // ---- issue cluster-0 reads (12) + first half of staging ----
#pragma unroll
        for (int nf = 0; nf < 4; ++nf) { bfr[nf][0] = DS_B(nf, 0); bfr[nf][1] = DS_B(nf, 1); }
        a0[0][0] = DS_A(0, 0); a0[0][1] = DS_A(0, 1);
        a0[1][0] = DS_A(1, 0); a0[1][1] = DS_A(1, 1);
        if (pf) { STAGE_A(b ^ 1, 0, t + 1); STAGE_B(b ^ 1, 0, t + 1); }

        // ---- issue cluster-1 reads (4) + second half of staging ----
        a1[0][0] = DS_A(2, 0); a1[0][1] = DS_A(2, 1);
        a1[1][0] = DS_A(3, 0); a1[1][1] = DS_A(3, 1);
        if (pf) { STAGE_A(b ^ 1, 1, t + 1); STAGE_B(b ^ 1, 1, t + 1); }

        WAITK4;                 // 12 oldest (bfr + a0) done, a1 in flight
        MFMA_CL(0, a0)

        a0[0][0] = DS_A(4, 0); a0[0][1] = DS_A(4, 1);
        a0[1][0] = DS_A(5, 0); a0[1][1] = DS_A(5, 1);
        WAITK4;                 // a1 done, a0(45) in flight
        MFMA_CL(2, a1)

        a1[0][0] = DS_A(6, 0); a1[0][1] = DS_A(6, 1);
        a1[1][0] = DS_A(7, 0); a1[1][1] = DS_A(7, 1);
        WAITK4;                 // a0(45) done, a1(67) in flight
        MFMA_CL(4, a0)

        WAITK0;                 // a1(67) done
        MFMA_CL(6, a1)

        if (pf) {
            // own staging loads issued ~one full tile ago -> effectively counted
            asm volatile("s_waitcnt vmcnt(0)" ::: "memory");
            __builtin_amdgcn_s_barrier();
        }
    }

    // ---- epilogue: D[row = quad*4 + i][col = r] per 16x16 frag ----
#pragma unroll
    for (int mf = 0; mf < 8; ++mf) {
#pragma unroll
        for (int i = 0; i < 4; ++i) {
            long m = bm0 + wr * 128 + mf * 16 + quad * 4 + i;
            if (F32OUT) {
                float* crow = (float*)Cout + m * (long)N + bn0 + wc * 64 + r;
#pragma unroll
                for (int nf = 0; nf < 4; ++nf) crow[nf * 16] = acc[mf][nf][i];
            } else {
                uint16_t* crow = (uint16_t*)Cout + m * (long)N + bn0 + wc * 64 + r;
#pragma unroll
                for (int nf = 0; nf < 4; ++nf) crow[nf * 16] = f2bf(acc[mf][nf][i]);
            }
        }
    }
#undef STAGE_A
#undef STAGE_B
#undef DS_A
#undef DS_B
#undef WAITK4
#undef WAITK0
#undef MFMA_CL
}

// ---------------------------------------------------------------------------
// Local window attention, LDS-staged K/V with zero-filled halo rows.
// Block = (bn, head), 256 threads, thread = s.
//
// LDS: K tile + V tile, each 262 halo rows (s = -3..258) x 64 elems bf16
// = 2 * 262 * 128 B = 65.5 KB (2 blocks/CU, unchanged).
// Halo rows are ZERO: reference pads K/V with zeros, so out-of-range window
// entries give score = 0*q + bias and contribute 0*p to the output -- the
// exact same math as the old guarded version, but with NO branches: all
// 112 inner ds_read_b128 are unconditional and fully unrolled, so the
// scheduler can pipeline them (old version: 56 exec-masked islands).
//
// Staging is global_load_lds DMA (no VGPR round-trip): LDS dest is linear
// (base + lane*16 -- verified linear across the +3-row halo offset), the
// XOR swizzle (chunk cc holds source chunk cc ^ (hrow&7)) is applied to the
// per-lane GLOBAL source address (m173 pattern). Compute reads use the same
// XOR -> conflict-free stride-128B reads, as before.
// ---------------------------------------------------------------------------
__global__ __launch_bounds__(256, 2)
void local_attn(const uint16_t* __restrict__ qkv, const float* __restrict__ pb,
                uint16_t* __restrict__ attn) {
    // [0,2096): K chunks (262 rows x 8), [2096,4192): V chunks
    __shared__ __align__(16) uint4 smem[4192];

    const int h  = blockIdx.x & 7;
    const int bn = blockIdx.x >> 3;
    const int s  = threadIdx.x;
    const int tid = threadIdx.x;
    const size_t base = (size_t)bn * 256 * 1536;

    // ---- own Q row (8 x 16B = 128 B), issued first so latency overlaps staging
    const uint16_t* qrow = qkv + base + (size_t)s * 1536 + h * 64;
    uint4 qc[8];
#pragma unroll
    for (int c = 0; c < 8; ++c) qc[c] = *(const uint4*)(qrow + c * 8);

    // ---- zero-fill halo rows: 6 rows x 8 chunks x 2 arrays = 96 chunks ----
    if (tid < 96) {
        int a    = tid / 48;            // 0=K, 1=V
        int rem  = tid - a * 48;        // 0..47
        int hr6  = rem >> 3;            // 0..5
        int c8   = rem & 7;
        int hrow = (hr6 < 3) ? hr6 : (256 + hr6);  // 0,1,2,259,260,261
        smem[a * 2096 + hrow * 8 + c8] = (uint4){0u, 0u, 0u, 0u};
    }

    // ---- stage K,V rows 0..255 -> halo rows 3..258 via global_load_lds DMA.
    // dest byte offset = a*33536 + (sp+3)*128 + (i&7)*16, linear in i (slope
    // 16 B/lane within each 2048-chunk array; array switch at i=2048 falls on
    // a wave boundary). Source chunk is pre-swizzled: cs = (i&7) ^ ((sp+3)&7).
#pragma unroll
    for (int it = 0; it < 16; ++it) {
        int i   = tid + it * 256;
        int a   = i >> 11;        // 0=K, 1=V
        int idx = i & 2047;
        int sp  = idx >> 3;
        int cs  = (i & 7) ^ ((sp + 3) & 7);
        const uint16_t* src = qkv + base + (size_t)sp * 1536 + 512 + a * 512 + h * 64 + cs * 8;
        GLOAD_LDS16(src, (uint16_t*)&smem[a * 2096 + (sp + 3) * 8 + (i & 7)]);
    }

    __syncthreads();  // drains DMA (vmcnt) + halo ds_writes (lgkmcnt)

    // ---- scores: hrow = s+w spans [s, s+6] in [0,262), branchless ----
    float sc[7];
#pragma unroll
    for (int w = 0; w < 7; ++w) sc[w] = 0.f;

#pragma unroll
    for (int c = 0; c < 8; ++c) {
        float qf[8];
        unpack8(qc[c], qf);
        uint4 kc[7];
#pragma unroll
        for (int w = 0; w < 7; ++w) {
            int hrow = s + w;
            kc[w] = smem[hrow * 8 + (c ^ (hrow & 7))];
        }
#pragma unroll
        for (int w = 0; w < 7; ++w) {
            float kf[8];
            unpack8(kc[w], kf);
#pragma unroll
            for (int j = 0; j < 8; ++j) sc[w] += qf[j] * kf[j];
        }
    }

    const float* pbr = pb + ((size_t)h * 256 + s) * 7;
    float mx = -1e30f;
#pragma unroll
    for (int w = 0; w < 7; ++w) {
        sc[w] = sc[w] * 0.125f + pbr[w];
        mx = fmaxf(mx, sc[w]);
    }
    float p[7], sum = 0.f;
#pragma unroll
    for (int w = 0; w < 7; ++w) {
        p[w] = __expf(sc[w] - mx);
        sum += p[w];
    }
    const float inv = 1.f / sum;
#pragma unroll
    for (int w = 0; w < 7; ++w) p[w] *= inv;

    // ---- output: branchless (halo V rows are zero), one 128-B store ----
    uint4 ov[8];
#pragma unroll
    for (int c = 0; c < 8; ++c) {
        uint4 vc[7];
#pragma unroll
        for (int w = 0; w < 7; ++w) {
            int hrow = s + w;
            vc[w] = smem[2096 + hrow * 8 + (c ^ (hrow & 7))];
        }
        float o[8] = {0.f, 0.f, 0.f, 0.f, 0.f, 0.f, 0.f, 0.f};
#pragma unroll
        for (int w = 0; w < 7; ++w) {
            float vf[8];
            unpack8(vc[w], vf);
#pragma unroll
            for (int j = 0; j < 8; ++j) o[j] += p[w] * vf[j];
        }
        ov[c].x = pack2(o[0], o[1]);
        ov[c].y = pack2(o[2], o[3]);
        ov[c].z = pack2(o[4], o[5]);
        ov[c].w = pack2(o[6], o[7]);
    }

    uint16_t* orow = attn + ((size_t)(bn * 256 + s)) * 512 + h * 64;
#pragma unroll
    for (int c = 0; c < 8; ++c) *(uint4*)(orow + c * 8) = ov[c];
}

// ---------------------------------------------------------------------------
extern "C" void kernel_launch(void* const* d_in, const int* in_sizes, int n_in,
                              void* d_out, int out_size, void* d_ws, size_t ws_size,
                              hipStream_t stream) {
    const float* X    = (const float*)d_in[0];  // 32768 x 512 fp32
    const float* pb   = (const float*)d_in[1];  // 8 x 256 x 7 fp32
    const float* Wqkv = (const float*)d_in[2];  // 512 x 1536 fp32
    const float* Wout = (const float*)d_in[3];  // 512 x 512 fp32
    float* out = (float*)d_out;                 // 32768 x 512 fp32

    char* ws = (char*)d_ws;
    uint16_t* WqkvT = (uint16_t*)(ws);                  // 1536x512 bf16 = 1.5 MB
    uint16_t* WoutT = (uint16_t*)(ws + 1572864);        // 512x512  bf16 = 0.5 MB
    uint16_t* qkvb  = (uint16_t*)(ws + 2097152);        // 32768x1536 bf16 = 96 MB
    uint16_t* Xb    = (uint16_t*)(ws + 102760448);      // 32768x512 bf16 = 32 MB
    uint16_t* attnb = Xb;  // alias: Xb dead after GEMM1 (stream-ordered)

    cvt_f32_bf16<<<(32768 * 512 / 8 + 255) / 256, 256, 0, stream>>>(X, Xb, 32768 * 512 / 8);
    transpose_cvt<<<(512 * 1536 + 255) / 256, 256, 0, stream>>>(Wqkv, WqkvT, 512, 1536);
    transpose_cvt<<<(512 * 512 + 255) / 256, 256, 0, stream>>>(Wout, WoutT, 512, 512);

    gemm256<false><<<dim3(128, 6), 512, 0, stream>>>(Xb, WqkvT, qkvb, 32768, 1536, 512);
    local_attn<<<1024, 256, 0, stream>>>(qkvb, pb, attnb);
    gemm256<true><<<dim3(128, 2), 512, 0, stream>>>(attnb, WoutT, out, 32768, 512, 512);
}